// Round 2
// baseline (511.599 us; speedup 1.0000x reference)
//
#include <hip/hip_runtime.h>
#include <stdint.h>

// Problem constants: B=8, S=2048, IN=4096, OUT=64, L=16
#define NB   8
#define NS   2048
#define NIN  4096
#define NOUT 64
#define NL   16

constexpr int MT  = 16;        // rows (m) per block
constexpr int KT  = 64;        // k per pipeline tile
constexpr int NKT = NIN / KT;  // 64 tiles

typedef __attribute__((ext_vector_type(8))) short  s16x8;   // MFMA A/B frag (8 bf16)
typedef __attribute__((ext_vector_type(4))) float  f32x4;   // MFMA acc
typedef __attribute__((ext_vector_type(4))) float  fv4;
typedef __attribute__((ext_vector_type(4))) __bf16 bf16x4;

// 8 fp32 -> 8 bf16 (RNE). __builtin_convertvector lowers to v_cvt_pk_bf16_f32
// on gfx950 (1 instr / 2 elems) instead of the ~5-op manual RNE sequence.
__device__ __forceinline__ s16x8 cvt8(float4 a, float4 b) {
    fv4 va = {a.x, a.y, a.z, a.w};
    fv4 vb = {b.x, b.y, b.z, b.w};
    union { struct { bf16x4 lo, hi; } h; s16x8 s; } u;
    u.h.lo = __builtin_convertvector(va, bf16x4);
    u.h.hi = __builtin_convertvector(vb, bf16x4);
    return u.s;
}

// Load one K=64 tile's worth of per-lane data (4 float4 = 16 fp32):
// elems [tt*64 + {0..7}] (step 0) and [tt*64 + {32..39}] (step 1), relative
// to a per-lane base that already includes row*NIN + (lane>>4)*8.
#define LOAD_TILE(dst, base, tt)                                  \
    {                                                             \
        const float4* _p = (const float4*)((base) + (tt) * KT);   \
        dst[0] = _p[0]; dst[1] = _p[1];                           \
        dst[2] = _p[8]; dst[3] = _p[9];                           \
    }

// Barrier-free multi-LoRA linear.
// Grid: 1024 blocks = 8 batches (XCD-affine, bx&7) x 128 m-tiles of 16 rows.
// Block: 256 threads = 4 waves; wave wv computes out[16 rows][wv*16..+16).
// Per K=32 step: acc = mfma_16x16x32_bf16(A-frag, B-frag, acc).
//   A-frag: x[m = lane&15][k = (lane>>4)*8 + j]   (converted fp32->bf16)
//   B-frag: w[n = lane&15 + wv*16][same k]        (weight is [OUT][IN] k-major)
//   D:      col = lane&15, row = (lane>>4)*4 + reg   (verified round 1)
__global__ __launch_bounds__(256, 4) void mll_kernel(const float* __restrict__ x,
                                                     const int* __restrict__ ids,
                                                     const float* __restrict__ w,
                                                     float* __restrict__ out) {
    const int bx   = blockIdx.x;
    const int b    = bx & 7;       // batch  (XCD-affine: each XCD -> 1 adapter)
    const int mt   = bx >> 3;      // m-tile 0..127
    const int aid  = ids[b];
    const int t    = threadIdx.x;
    const int lane = t & 63;
    const int wv   = t >> 6;       // 0..3 -> output col group
    const int l15  = lane & 15;
    const int lk   = lane >> 4;    // 0..3 -> k-group

    const float* pa = x + ((size_t)(b * NS + mt * MT + l15)) * NIN + lk * 8;
    const float* pb = w + ((size_t)(aid * NOUT + wv * 16 + l15)) * NIN + lk * 8;

    f32x4 acc = {0.f, 0.f, 0.f, 0.f};

    // 2-stage register pipeline: stage s holds tile (t + s); loads for t+2
    // are issued right after stage regs are consumed -> ~2 iterations of
    // lead time, no barriers anywhere so waves slide independently.
    float4 a0[4], b0[4], a1[4], b1[4];
    LOAD_TILE(a0, pa, 0); LOAD_TILE(b0, pb, 0);
    LOAD_TILE(a1, pa, 1); LOAD_TILE(b1, pb, 1);

    for (int tt = 0; tt < NKT - 2; tt += 2) {
        // ---- stage 0: tile tt
        {
            s16x8 af0 = cvt8(a0[0], a0[1]), bf0 = cvt8(b0[0], b0[1]);
            s16x8 af1 = cvt8(a0[2], a0[3]), bf1 = cvt8(b0[2], b0[3]);
            LOAD_TILE(a0, pa, tt + 2); LOAD_TILE(b0, pb, tt + 2);
            acc = __builtin_amdgcn_mfma_f32_16x16x32_bf16(af0, bf0, acc, 0, 0, 0);
            acc = __builtin_amdgcn_mfma_f32_16x16x32_bf16(af1, bf1, acc, 0, 0, 0);
        }
        // ---- stage 1: tile tt+1
        {
            s16x8 af0 = cvt8(a1[0], a1[1]), bf0 = cvt8(b1[0], b1[1]);
            s16x8 af1 = cvt8(a1[2], a1[3]), bf1 = cvt8(b1[2], b1[3]);
            LOAD_TILE(a1, pa, tt + 3); LOAD_TILE(b1, pb, tt + 3);
            acc = __builtin_amdgcn_mfma_f32_16x16x32_bf16(af0, bf0, acc, 0, 0, 0);
            acc = __builtin_amdgcn_mfma_f32_16x16x32_bf16(af1, bf1, acc, 0, 0, 0);
        }
    }
    // ---- epilogue tiles 62, 63 (already in regs)
    {
        s16x8 af0 = cvt8(a0[0], a0[1]), bf0 = cvt8(b0[0], b0[1]);
        s16x8 af1 = cvt8(a0[2], a0[3]), bf1 = cvt8(b0[2], b0[3]);
        acc = __builtin_amdgcn_mfma_f32_16x16x32_bf16(af0, bf0, acc, 0, 0, 0);
        acc = __builtin_amdgcn_mfma_f32_16x16x32_bf16(af1, bf1, acc, 0, 0, 0);
        af0 = cvt8(a1[0], a1[1]); bf0 = cvt8(b1[0], b1[1]);
        af1 = cvt8(a1[2], a1[3]); bf1 = cvt8(b1[2], b1[3]);
        acc = __builtin_amdgcn_mfma_f32_16x16x32_bf16(af0, bf0, acc, 0, 0, 0);
        acc = __builtin_amdgcn_mfma_f32_16x16x32_bf16(af1, bf1, acc, 0, 0, 0);
    }

    // ---- store: D col = lane&15 (n), row = (lane>>4)*4 + reg (m)
    float* ob = out + ((size_t)(b * NS + mt * MT)) * NOUT + wv * 16 + l15;
#pragma unroll
    for (int r = 0; r < 4; ++r) {
        ob[(size_t)(lk * 4 + r) * NOUT] = acc[r];
    }
}

extern "C" void kernel_launch(void* const* d_in, const int* in_sizes, int n_in,
                              void* d_out, int out_size, void* d_ws, size_t ws_size,
                              hipStream_t stream) {
    const float* x   = (const float*)d_in[0];
    const int*   ids = (const int*)d_in[1];
    const float* w   = (const float*)d_in[2];
    float*       out = (float*)d_out;

    const int grid = NB * (NS / MT);  // 1024
    mll_kernel<<<grid, 256, 0, stream>>>(x, ids, w, out);
}

// Round 3
// 375.459 us; speedup vs baseline: 1.3626x; 1.3626x over previous
//
#include <hip/hip_runtime.h>
#include <stdint.h>

// Problem constants: B=8, S=2048, IN=4096, OUT=64, L=16
#define NB   8
#define NS   2048
#define NIN  4096
#define NOUT 64
#define NL   16

constexpr int MT = 16;         // m rows per block
constexpr int KT = 128;        // k floats per tile
constexpr int NT = NIN / KT;   // 32 tiles

typedef __attribute__((ext_vector_type(8))) short  s16x8;   // MFMA A/B frag (8 bf16)
typedef __attribute__((ext_vector_type(4))) float  f32x4;   // MFMA acc
typedef __attribute__((ext_vector_type(4))) float  fv4;
typedef __attribute__((ext_vector_type(4))) __bf16 bf16x4;

// 8 fp32 -> 8 bf16 RNE via v_cvt_pk_bf16_f32 (1 inst / 2 elems).
__device__ __forceinline__ s16x8 cvt8(float4 a, float4 b) {
    fv4 va = {a.x, a.y, a.z, a.w};
    fv4 vb = {b.x, b.y, b.z, b.w};
    union { struct { bf16x4 lo, hi; } h; s16x8 s; } u;
    u.h.lo = __builtin_convertvector(va, bf16x4);
    u.h.hi = __builtin_convertvector(vb, bf16x4);
    return u.s;
}

// Pre-kernel: weight fp32 [16,64,4096] -> bf16 in ws. 8 elems/thread.
__global__ __launch_bounds__(256) void convert_w_kernel(const float* __restrict__ w,
                                                        unsigned short* __restrict__ o) {
    size_t i = ((size_t)blockIdx.x * 256 + threadIdx.x) * 8;
    const float4* src = (const float4*)(w + i);
    *(s16x8*)(o + i) = cvt8(src[0], src[1]);
}

// Multi-LoRA linear, m97-style: x staged fp32->bf16 into XOR-swizzled LDS,
// double-buffered, one __syncthreads per K=128 tile; latency hidden by
// 4 blocks/CU overlapping each other's barrier drains (m114 mechanism).
// Grid: 1024 = 8 batches (XCD-affine via bx&7) x 128 m-tiles of 16 rows.
// Block: 256 threads = 4 waves; wave wv computes out[16 m][wv*16 .. +16).
//   A-frag: x[m = lane&15][k = (lane>>4)*8 + j]  (bf16, from LDS)
//   B-frag: w[n = lane&15 + wv*16][same k]       (bf16, from global, L2-hot)
//   D:      col = lane&15 (n), row = (lane>>4)*4 + reg (m)   [verified r1]
template <bool WBF16>
__global__ __launch_bounds__(256, 4) void mll_kernel(const float* __restrict__ x,
                                                     const int* __restrict__ ids,
                                                     const void* __restrict__ wsel,
                                                     float* __restrict__ out) {
    // [2 buf][16 rows][128 bf16], 16B chunks XOR-swizzled by row -> 2-way banks (free)
    __shared__ __align__(16) unsigned short xs[2 * MT * KT];  // 8 KB

    const int bx   = blockIdx.x;
    const int b    = bx & 7;       // batch; round-robin dispatch -> XCD-affine
    const int mt   = bx >> 3;      // 0..127
    const int aid  = ids[b];
    const int t    = threadIdx.x;
    const int lane = t & 63;
    const int wv   = t >> 6;
    const int l15  = lane & 15;
    const int lk   = lane >> 4;    // 0..3

    // ---- staging coords: thread t loads row t>>4, 8-float chunk q = t&15
    const int srow = t >> 4;       // 0..15
    const int sq   = t & 15;       // 0..15
    const float* gsrc = x + ((size_t)(b * NS + mt * MT + srow)) * NIN + sq * 8;
    const int woff = srow * KT + ((sq ^ srow) * 8);   // swizzled LDS elem offset

    // ---- A-frag LDS read offsets (per K=32 step s: chunk q = s*4+lk)
    int roff[4];
#pragma unroll
    for (int s = 0; s < 4; ++s) roff[s] = l15 * KT + (((s * 4 + lk) ^ l15) * 8);

    // ---- B pointers (bf16 fast path / fp32 fallback)
    const unsigned short* wb16 = nullptr;
    const float*          wb32 = nullptr;
    if (WBF16) wb16 = (const unsigned short*)wsel + ((size_t)(aid * NOUT + wv * 16 + l15)) * NIN + lk * 8;
    else       wb32 = (const float*)wsel          + ((size_t)(aid * NOUT + wv * 16 + l15)) * NIN + lk * 8;

    f32x4 acc = {0.f, 0.f, 0.f, 0.f};

#define LOAD_B(dst, tt)                                                        \
    if (WBF16) {                                                               \
        _Pragma("unroll")                                                      \
        for (int s = 0; s < 4; ++s)                                            \
            dst[s] = *(const s16x8*)(wb16 + (size_t)(tt) * KT + s * 32);       \
    } else {                                                                   \
        _Pragma("unroll")                                                      \
        for (int s = 0; s < 4; ++s) {                                          \
            const float4* _wp = (const float4*)(wb32 + (size_t)(tt) * KT + s * 32); \
            dst[s] = cvt8(_wp[0], _wp[1]);                                     \
        }                                                                      \
    }

    // ---- prologue: tile 0 -> LDS buf0; tile 1 -> regs; B tile 0 -> regs
    {
        const float4* g0 = (const float4*)gsrc;
        *(s16x8*)(xs + woff) = cvt8(g0[0], g0[1]);
    }
    const float4* g1 = (const float4*)(gsrc + KT);
    float4 r0 = g1[0], r1 = g1[1];
    s16x8 bcur[4], bnext[4];
    LOAD_B(bcur, 0);
    __syncthreads();

    for (int tile = 0; tile < NT; ++tile) {
        const int p = tile & 1;

        // prefetch x tile+2 (clamped; tail reload harmless) — used next iter's write
        const int pt = (tile + 2 < NT) ? (tile + 2) : (NT - 1);
        const float4* gn = (const float4*)(gsrc + (size_t)pt * KT);
        float4 n0 = gn[0], n1 = gn[1];

        // prefetch B tile+1 (clamped)
        const int bt = (tile + 1 < NT) ? (tile + 1) : (NT - 1);
        LOAD_B(bnext, bt);

        // compute tile from LDS buf p (4 K=32 MFMA steps)
        const unsigned short* buf = xs + p * (MT * KT);
#pragma unroll
        for (int s = 0; s < 4; ++s) {
            s16x8 af = *(const s16x8*)(buf + roff[s]);
            acc = __builtin_amdgcn_mfma_f32_16x16x32_bf16(af, bcur[s], acc, 0, 0, 0);
        }

        // stage tile+1 (in r0/r1 since last iter) into the other buffer
        if (tile + 1 < NT) {
            *(s16x8*)(xs + (1 - p) * (MT * KT) + woff) = cvt8(r0, r1);
        }
        r0 = n0; r1 = n1;
#pragma unroll
        for (int s = 0; s < 4; ++s) bcur[s] = bnext[s];
        __syncthreads();
    }
#undef LOAD_B

    // ---- store: D col = lane&15 (n), row = (lane>>4)*4 + reg (m)
    float* ob = out + ((size_t)(b * NS + mt * MT)) * NOUT + wv * 16 + l15;
#pragma unroll
    for (int r = 0; r < 4; ++r) {
        ob[(size_t)(lk * 4 + r) * NOUT] = acc[r];
    }
}

extern "C" void kernel_launch(void* const* d_in, const int* in_sizes, int n_in,
                              void* d_out, int out_size, void* d_ws, size_t ws_size,
                              hipStream_t stream) {
    const float* x   = (const float*)d_in[0];
    const int*   ids = (const int*)d_in[1];
    const float* w   = (const float*)d_in[2];
    float*       out = (float*)d_out;

    const size_t wbytes = (size_t)NL * NOUT * NIN * sizeof(unsigned short);  // 8.4 MB
    const int grid = NB * (NS / MT);  // 1024

    if (ws_size >= wbytes) {
        unsigned short* wbf = (unsigned short*)d_ws;
        const int n = NL * NOUT * NIN;                      // 4,194,304
        convert_w_kernel<<<n / (256 * 8), 256, 0, stream>>>(w, wbf);
        mll_kernel<true><<<grid, 256, 0, stream>>>(x, ids, wbf, out);
    } else {
        mll_kernel<false><<<grid, 256, 0, stream>>>(x, ids, w, out);
    }
}